// Round 5
// baseline (291.156 us; speedup 1.0000x reference)
//
#include <hip/hip_runtime.h>
#include <hip/hip_bf16.h>

#define B_    8
#define N_    2048
#define DIN_  512
#define DOUT_ 256
#define NBUCK 20

typedef __attribute__((ext_vector_type(8))) short  short8;
typedef __attribute__((ext_vector_type(4))) float  floatx4;

__device__ __forceinline__ unsigned short f2b(float f) {
    __hip_bfloat16 h = __float2bfloat16(f);
    unsigned short u;
    __builtin_memcpy(&u, &h, 2);
    return u;
}

// ---------------- wvs = Wv^T . Ws (512 floats), bvs = bv . Ws ----------------
__global__ __launch_bounds__(128) void wvs_kernel(const float* __restrict__ Wv,
                                                  const float* __restrict__ Ws,
                                                  const float* __restrict__ bv,
                                                  float* __restrict__ wvs,
                                                  float* __restrict__ bvs) {
    __shared__ float wsl[DOUT_];
    int tid = threadIdx.x;
    wsl[tid] = Ws[tid];
    wsl[tid + 128] = Ws[tid + 128];
    __syncthreads();
    int d = blockIdx.x * 128 + tid;
    float s = 0.f;
#pragma unroll 8
    for (int o = 0; o < DOUT_; ++o) s += Wv[(size_t)o * DIN_ + d] * wsl[o];
    wvs[d] = s;
    if (blockIdx.x == 0 && tid < 64) {
        float bb = wsl[tid] * bv[tid] + wsl[tid + 64] * bv[tid + 64] +
                   wsl[tid + 128] * bv[tid + 128] + wsl[tid + 192] * bv[tid + 192];
        for (int off = 1; off < 64; off <<= 1) bb += __shfl_xor(bb, off, 64);
        if (tid == 0) *bvs = bb;
    }
}

// ---------------- x -> bf16, fused vw = x . wvs + bvs ----------------
__global__ __launch_bounds__(256) void cvt_x_kernel(const float* __restrict__ x,
                                                    const float* __restrict__ wvs,
                                                    const float* __restrict__ bvs,
                                                    unsigned short* __restrict__ xb,
                                                    float* __restrict__ vw) {
    int tid = threadIdx.x, wave = tid >> 6, lane = tid & 63;
    int row = blockIdx.x * 4 + wave;
    size_t base = (size_t)row * DIN_ + lane * 8;
    float4 a = *(const float4*)(x + base);
    float4 b = *(const float4*)(x + base + 4);
    float4 wa = *(const float4*)(wvs + lane * 8);
    float4 wb = *(const float4*)(wvs + lane * 8 + 4);
    uint4 r;
    r.x = f2b(a.x) | ((unsigned)f2b(a.y) << 16);
    r.y = f2b(a.z) | ((unsigned)f2b(a.w) << 16);
    r.z = f2b(b.x) | ((unsigned)f2b(b.y) << 16);
    r.w = f2b(b.z) | ((unsigned)f2b(b.w) << 16);
    *(uint4*)(xb + base) = r;
    float d = a.x * wa.x + a.y * wa.y + a.z * wa.z + a.w * wa.w +
              b.x * wb.x + b.y * wb.y + b.z * wb.z + b.w * wb.w;
    for (int off = 1; off < 64; off <<= 1) d += __shfl_xor(d, off, 64);
    if (lane == 0) vw[row] = d + *bvs;
}

// ---------------- Wq,Wk -> bf16 ----------------
__global__ __launch_bounds__(256) void cvt_w_kernel(const float* __restrict__ wq,
                                                    const float* __restrict__ wk,
                                                    unsigned short* __restrict__ dst) {
    int i = (blockIdx.x * 256 + threadIdx.x) * 8;  // 0 .. 262144-8
    const float* src = (i < 131072) ? (wq + i) : (wk + (i - 131072));
    float4 a = *(const float4*)(src);
    float4 b = *(const float4*)(src + 4);
    uint4 r;
    r.x = f2b(a.x) | ((unsigned)f2b(a.y) << 16);
    r.y = f2b(a.z) | ((unsigned)f2b(a.w) << 16);
    r.z = f2b(b.x) | ((unsigned)f2b(b.y) << 16);
    r.w = f2b(b.z) | ((unsigned)f2b(b.w) << 16);
    *(uint4*)(dst + i) = r;
}

// ---------------- Q,K GEMM ----------------
// grid (128, 8): x = 128-row block (32 rows/wave), y = 64-col block of 512 outputs.
// Fully unrolled K-loop so the compiler software-pipelines the global loads.
__global__ __launch_bounds__(256, 4) void qkv_kernel(
    const unsigned short* __restrict__ xb, const unsigned short* __restrict__ wb,
    const float* __restrict__ bq, const float* __restrict__ bk,
    unsigned short* __restrict__ q, unsigned short* __restrict__ k) {
    const int tid  = threadIdx.x;
    const int wave = tid >> 6, lane = tid & 63, quad = lane >> 4, l16 = lane & 15;
    const int row0 = blockIdx.x * 128 + wave * 32;
    const int col0 = blockIdx.y * 64;

    floatx4 acc[2][4];
#pragma unroll
    for (int a = 0; a < 2; ++a)
#pragma unroll
        for (int t = 0; t < 4; ++t) acc[a][t] = (floatx4){0.f, 0.f, 0.f, 0.f};

    const unsigned short* arow0 = xb + (size_t)(row0 + l16) * DIN_ + quad * 8;
    const unsigned short* arow1 = xb + (size_t)(row0 + 16 + l16) * DIN_ + quad * 8;
    const unsigned short* brow  = wb + (size_t)(col0 + l16) * DIN_ + quad * 8;
#pragma unroll
    for (int kc = 0; kc < DIN_; kc += 32) {
        short8 af0 = *(const short8*)(arow0 + kc);
        short8 af1 = *(const short8*)(arow1 + kc);
#pragma unroll
        for (int ct = 0; ct < 4; ++ct) {
            short8 bf = *(const short8*)(brow + (size_t)ct * 16 * DIN_ + kc);
            acc[0][ct] = __builtin_amdgcn_mfma_f32_16x16x32_bf16(af0, bf, acc[0][ct], 0, 0, 0);
            acc[1][ct] = __builtin_amdgcn_mfma_f32_16x16x32_bf16(af1, bf, acc[1][ct], 0, 0, 0);
        }
    }
#pragma unroll
    for (int ct = 0; ct < 4; ++ct) {
        int col = col0 + ct * 16 + l16;
        unsigned short* dst = (col < 256) ? q : k;
        float bias = (col < 256) ? bq[col] : bk[col - 256];
        int c = col & 255;
#pragma unroll
        for (int a = 0; a < 2; ++a)
#pragma unroll
            for (int r = 0; r < 4; ++r) {
                int row = row0 + a * 16 + quad * 4 + r;
                dst[(size_t)row * DOUT_ + c] = f2b(acc[a][ct][r] + bias);
            }
    }
}

// ---------------- gated flash attention, scalarized V path ----------------
// grid 512: b = g&7 (XCD-affine), rblk = g>>3 -> 32 q-rows.
// 512 threads = 8 waves = 8 m-splits of 256 columns. Fully unrolled m-loop so
// the compiler hoists next-iteration K loads above the exp section
// (software pipelining within the __launch_bounds__ register budget).
// Gate bucket via float math: ranks < 2048 are exact in fp32; k*5*0.2f
// rounds to exactly k, so trunc gives floor(d/5) exactly.
__global__ __launch_bounds__(512, 4) void attn_kernel(
    const unsigned short* __restrict__ q, const unsigned short* __restrict__ k,
    const float* __restrict__ vw, const int* __restrict__ pr,
    const float* __restrict__ rank_emb, const float* __restrict__ rank_w,
    const float* __restrict__ bs, const float* __restrict__ bvs,
    float* __restrict__ out) {
    const int g = blockIdx.x;
    const int b = g & 7, rblk = g >> 3;
    const int tid = threadIdx.x, wave = tid >> 6, lane = tid & 63;
    const int quad = lane >> 4, l16 = lane & 15;
    const int sp = wave;            // m split 0..7
    const int n0 = rblk * 32;

    __shared__ float gtab[NBUCK];
    __shared__ float lL[8][32], wdL[8][32];

    if (tid < NBUCK)  // scale * log2e folded in
        gtab[tid] = 0.0625f * 1.44269504f / (1.f + __expf(-rank_w[0] * rank_emb[tid]));
    __syncthreads();

    const unsigned short* qb = q + (size_t)b * N_ * DOUT_;
    const unsigned short* kb = k + (size_t)b * N_ * DOUT_;
    const float* vwb = vw + b * N_;
    const int* prb = pr + b * N_;

    short8 qf[2][8];
#pragma unroll
    for (int a = 0; a < 2; ++a)
#pragma unroll
        for (int c = 0; c < 8; ++c)
            qf[a][c] = *(const short8*)(qb + (size_t)(n0 + a * 16 + l16) * DOUT_ + c * 32 + quad * 8);

    float prn[2][4];
#pragma unroll
    for (int a = 0; a < 2; ++a)
#pragma unroll
        for (int r = 0; r < 4; ++r) prn[a][r] = (float)prb[n0 + a * 16 + quad * 4 + r];

    float lacc[2][4], wacc[2][4];
#pragma unroll
    for (int a = 0; a < 2; ++a)
#pragma unroll
        for (int r = 0; r < 4; ++r) { lacc[a][r] = 0.f; wacc[a][r] = 0.f; }

    const int mbeg = sp * 256;
#pragma unroll
    for (int mi = 0; mi < 8; ++mi) {
        const int m0 = mbeg + mi * 32;
        floatx4 s[2][2];
#pragma unroll
        for (int a = 0; a < 2; ++a)
#pragma unroll
            for (int h = 0; h < 2; ++h) s[a][h] = (floatx4){0.f, 0.f, 0.f, 0.f};
#pragma unroll
        for (int h = 0; h < 2; ++h) {
            const unsigned short* krow = kb + (size_t)(m0 + h * 16 + l16) * DOUT_ + quad * 8;
#pragma unroll
            for (int c = 0; c < 8; ++c) {
                short8 kf = *(const short8*)(krow + c * 32);
                s[0][h] = __builtin_amdgcn_mfma_f32_16x16x32_bf16(qf[0][c], kf, s[0][h], 0, 0, 0);
                s[1][h] = __builtin_amdgcn_mfma_f32_16x16x32_bf16(qf[1][c], kf, s[1][h], 0, 0, 0);
            }
        }
#pragma unroll
        for (int h = 0; h < 2; ++h) {
            int col = m0 + h * 16 + l16;
            float prm = (float)prb[col];
            float vwv = vwb[col];
#pragma unroll
            for (int a = 0; a < 2; ++a)
#pragma unroll
                for (int r = 0; r < 4; ++r) {
                    float d5 = fabsf(prn[a][r] - prm) * 0.2f;
                    int idx = (int)fminf(d5, 19.0f);
                    float p = exp2f(s[a][h][r] * gtab[idx]);
                    lacc[a][r] += p;
                    wacc[a][r] += p * vwv;
                }
        }
    }

    // merge partial (l, wd) across the 16 column-lanes
#pragma unroll
    for (int off = 1; off < 16; off <<= 1) {
#pragma unroll
        for (int a = 0; a < 2; ++a)
#pragma unroll
            for (int r = 0; r < 4; ++r) {
                lacc[a][r] += __shfl_xor(lacc[a][r], off, 64);
                wacc[a][r] += __shfl_xor(wacc[a][r], off, 64);
            }
    }
    if (l16 == 0) {
#pragma unroll
        for (int a = 0; a < 2; ++a)
#pragma unroll
            for (int r = 0; r < 4; ++r) {
                int row = a * 16 + quad * 4 + r;
                lL[sp][row]  = lacc[a][r];
                wdL[sp][row] = wacc[a][r];
            }
    }
    __syncthreads();
    if (tid < 32) {
        float l = 0.f, wd = 0.f;
#pragma unroll
        for (int s2 = 0; s2 < 8; ++s2) { l += lL[s2][tid]; wd += wdL[s2][tid]; }
        float logit = wd / l + *bvs + bs[0];
        out[(size_t)b * N_ + n0 + tid] = 1.f / (1.f + __expf(-logit));
    }
}

// ---------------- launch ----------------
extern "C" void kernel_launch(void* const* d_in, const int* in_sizes, int n_in,
                              void* d_out, int out_size, void* d_ws, size_t ws_size,
                              hipStream_t stream) {
    const float* x   = (const float*)d_in[0];
    const int*   pr  = (const int*)d_in[1];
    const float* Wq  = (const float*)d_in[2];
    const float* bq  = (const float*)d_in[3];
    const float* Wk  = (const float*)d_in[4];
    const float* bk  = (const float*)d_in[5];
    const float* Wv  = (const float*)d_in[6];
    const float* bv  = (const float*)d_in[7];
    const float* Ws  = (const float*)d_in[8];
    const float* bs  = (const float*)d_in[9];
    const float* remb = (const float*)d_in[10];
    const float* rw   = (const float*)d_in[11];
    float* out = (float*)d_out;

    char* ws = (char*)d_ws;
    unsigned short* xb  = (unsigned short*)ws;                    // 16,777,216 B
    unsigned short* wb  = (unsigned short*)(ws + 16777216);       //    524,288 B
    unsigned short* q   = (unsigned short*)(ws + 17301504);       //  8,388,608 B
    unsigned short* kk  = (unsigned short*)(ws + 25690112);       //  8,388,608 B
    float*          vwp = (float*)(ws + 34078720);                //     65,536 B
    float*          wvs = (float*)(ws + 34144256);                //      2,048 B
    float*          bvs = (float*)(ws + 34146304);                //          4 B

    hipLaunchKernelGGL(wvs_kernel, dim3(4), dim3(128), 0, stream, Wv, Ws, bv, wvs, bvs);
    hipLaunchKernelGGL(cvt_x_kernel, dim3(4096), dim3(256), 0, stream, x, wvs, bvs, xb, vwp);
    hipLaunchKernelGGL(cvt_w_kernel, dim3(128), dim3(256), 0, stream, Wq, Wk, wb);
    hipLaunchKernelGGL(qkv_kernel, dim3(128, 8), dim3(256), 0, stream,
                       xb, wb, bq, bk, q, kk);
    hipLaunchKernelGGL(attn_kernel, dim3(512), dim3(512), 0, stream,
                       q, kk, vwp, pr, remb, rw, bs, bvs, out);
}